// Round 3
// baseline (963.073 us; speedup 1.0000x reference)
//
#include <hip/hip_runtime.h>
#include <hip/hip_bf16.h>
#include <math.h>
#include <stdint.h>

#define N_ROWS 8192
#define M_FACTS 8192
#define D_DIM 1024

typedef __bf16 bf16x8_t __attribute__((ext_vector_type(8)));
typedef __bf16 bf16x4_t __attribute__((ext_vector_type(4)));
typedef float f32x4_t __attribute__((ext_vector_type(4)));

#define BM 128
#define BN 128
#define BK 32
#define PADK 40  // legacy padded stride for fallback kernels

// Async global->LDS, 16B per lane. LDS dest = wave-uniform base + lane*16.
__device__ __forceinline__ void gload_lds16(const void* g, void* lds) {
  __builtin_amdgcn_global_load_lds(
      (__attribute__((address_space(1))) void*)(uintptr_t)g,
      (__attribute__((address_space(3))) void*)(uint32_t)(uintptr_t)lds,
      16, 0, 0);
}

// =========================================================================
// Precompute kernels
// =========================================================================

__global__ __launch_bounds__(256) void split_hi_lo(const float* __restrict__ X,
                                                   __bf16* __restrict__ H,
                                                   __bf16* __restrict__ L) {
  int i = blockIdx.x * 256 + threadIdx.x;
  float4 v = ((const float4*)X)[i];
  float f[4] = {v.x, v.y, v.z, v.w};
  bf16x4_t h, l;
#pragma unroll
  for (int q = 0; q < 4; q++) {
    __bf16 hh = (__bf16)f[q];
    h[q] = hh;
    l[q] = (__bf16)(f[q] - (float)hh);
  }
  ((bf16x4_t*)H)[i] = h;
  ((bf16x4_t*)L)[i] = l;
}

// E [N][1024] fp32 -> A2 [N][3072] bf16 = [Eh | El | Eh] (K-concat: the
// 3-product compensated GEMM becomes ONE standard bf16 GEMM with K=3072).
__global__ __launch_bounds__(256) void split_concat_E(const float* __restrict__ X,
                                                      __bf16* __restrict__ A2) {
  int idx = blockIdx.x * 256 + threadIdx.x;  // float4 index over N*1024/4
  int n = idx >> 8, d4 = idx & 255;
  float4 v = ((const float4*)X)[idx];
  float f[4] = {v.x, v.y, v.z, v.w};
  bf16x4_t h, l;
#pragma unroll
  for (int q = 0; q < 4; q++) {
    __bf16 hh = (__bf16)f[q];
    h[q] = hh;
    l[q] = (__bf16)(f[q] - (float)hh);
  }
  size_t base = (size_t)n * 3072 + d4 * 4;
  *(bf16x4_t*)(A2 + base) = h;
  *(bf16x4_t*)(A2 + base + 1024) = l;
  *(bf16x4_t*)(A2 + base + 2048) = h;
}

// F [M][1024] fp32 -> B2 [M][3072] bf16 = [Fh | Fh | Fl].
__global__ __launch_bounds__(256) void split_concat_F(const float* __restrict__ X,
                                                      __bf16* __restrict__ B2) {
  int idx = blockIdx.x * 256 + threadIdx.x;
  int m = idx >> 8, d4 = idx & 255;
  float4 v = ((const float4*)X)[idx];
  float f[4] = {v.x, v.y, v.z, v.w};
  bf16x4_t h, l;
#pragma unroll
  for (int q = 0; q < 4; q++) {
    __bf16 hh = (__bf16)f[q];
    h[q] = hh;
    l[q] = (__bf16)(f[q] - (float)hh);
  }
  size_t base = (size_t)m * 3072 + d4 * 4;
  *(bf16x4_t*)(B2 + base) = h;
  *(bf16x4_t*)(B2 + base + 1024) = h;
  *(bf16x4_t*)(B2 + base + 2048) = l;
}

// F fp32 [M][D] -> Ft bf16 [D][M]. 64x64 tiles; fp32 LDS tile stride 69.
__global__ __launch_bounds__(256) void transpose_f_bf16(const float* __restrict__ F,
                                                        __bf16* __restrict__ Ft) {
  __shared__ float t[64 * 69];
  const int tid = threadIdx.x;
  const int m0 = blockIdx.x * 64, d0 = blockIdx.y * 64;
#pragma unroll
  for (int p = 0; p < 4; p++) {
    int flat = p * 256 + tid;
    int m = flat >> 4, dq = flat & 15;
    float4 v = *(const float4*)(F + (size_t)(m0 + m) * D_DIM + d0 + dq * 4);
    t[(dq * 4 + 0) * 69 + m] = v.x;
    t[(dq * 4 + 1) * 69 + m] = v.y;
    t[(dq * 4 + 2) * 69 + m] = v.z;
    t[(dq * 4 + 3) * 69 + m] = v.w;
  }
  __syncthreads();
#pragma unroll
  for (int q = 0; q < 2; q++) {
    int id = q * 256 + tid;
    int d = id >> 3, c = id & 7;
    const float* row = t + d * 69 + c * 8;
    bf16x8_t o;
#pragma unroll
    for (int i = 0; i < 8; i++) o[i] = (__bf16)row[i];
    *(bf16x8_t*)(Ft + (size_t)(d0 + d) * M_FACTS + m0 + c * 8) = o;
  }
}

// =========================================================================
// 3-slot-ring counted-vmcnt B^T GEMM:  C[..][..] = A[*][K] * B[*][K]^T.
// BM=256, BN=128, BK=64. 512 thr = 8 waves (2M x 4N), per-wave C = 128x32.
// LDS = 3 ring slots x (A 32KB + B 16KB) = 147KB -> 1 block/CU, 8 waves.
//
// Ring schedule (T3+T4, counted vmcnt -- never drain to 0 in-loop):
//   compute tile t from slot t%3; during phase 0 of tile t, stage tile t+2
//   into slot (t+2)%3 == (t-1)%3 (free: tile t-1's reads finished at the
//   previous boundary barrier, and stages issue after it -> WAR-safe).
//   Boundary: s_waitcnt vmcnt(6) keeps tile t+2's 6 loads in flight and
//   waits only tile t+1's 6 loads -- issued TWO tiles (~640+ cyc) earlier,
//   so HBM latency is covered (RAW-safe: vmcnt+barrier publishes slot).
// Per tile: 2 phases x {12 ds_read | 16 MFMA in setprio(1)}, raw s_barrier
// (NOT __syncthreads -- that would re-insert the vmcnt(0) drain).
// Swizzle (T2): LDS[row][q] = G[row][q ^ (row&7)] via pre-swizzled global
// source (linear LDS dest), ds_read applies same XOR. Measured 0 conflicts.
// =========================================================================
__global__ __launch_bounds__(512, 2) void gemm_ring(const __bf16* __restrict__ A,
                                                    const __bf16* __restrict__ B,
                                                    float* __restrict__ C,
                                                    int K, int lda, int ldb, int ldc) {
  __shared__ __align__(16) __bf16 sA[3][256 * 64];
  __shared__ __align__(16) __bf16 sB[3][128 * 64];
  const int tid = threadIdx.x;  // 0..511
  const int wave = tid >> 6, lane = tid & 63;
  const int wm = wave >> 2;   // 0..1  (A half: rows wm*128..+127)
  const int wn = wave & 3;    // 0..3  (C cols wn*32..+31)
  const int lrow = lane & 15, quad = lane >> 4;
  const int row0 = blockIdx.x * 256;
  const int col0 = blockIdx.y * 128;

  // Stage-granule maps (16B granules, linear LDS dest, swizzled source).
  // A: 256 rows x 8 granules = 2048 -> 4/thread. B: 128 x 8 = 1024 -> 2/thread.
  auto STAGE = [&](int slot, int kt) {
    const int ko = kt * 64;
#pragma unroll
    for (int k = 0; k < 4; k++) {
      int g = tid + 512 * k;
      int sr = g >> 3;
      int so = ((g & 7) ^ (sr & 7)) << 3;
      gload_lds16(A + (size_t)(row0 + sr) * lda + ko + so, &sA[slot][g * 8]);
    }
#pragma unroll
    for (int k = 0; k < 2; k++) {
      int g = tid + 512 * k;
      int sr = g >> 3;
      int so = ((g & 7) ^ (sr & 7)) << 3;
      gload_lds16(B + (size_t)(col0 + sr) * ldb + ko + so, &sB[slot][g * 8]);
    }
  };

  f32x4_t acc[8][2];
#pragma unroll
  for (int i = 0; i < 8; i++)
#pragma unroll
    for (int j = 0; j < 2; j++) acc[i][j] = (f32x4_t){0.f, 0.f, 0.f, 0.f};

  const int nkt = K >> 6;

  // Prologue: stage tiles 0,1; wait tile 0 only (6 newest stay in flight).
  STAGE(0, 0);
  STAGE(1, 1);
  asm volatile("s_waitcnt vmcnt(6)" ::: "memory");
  __builtin_amdgcn_s_barrier();
  __builtin_amdgcn_sched_barrier(0);

  int slot = 0;
  for (int t = 0; t < nkt; ++t) {
    const __bf16* lA = &sA[slot][0];
    const __bf16* lB = &sB[slot][0];
    const int slot2 = (slot == 0) ? 2 : slot - 1;  // (t+2)%3

#pragma unroll
    for (int p = 0; p < 2; ++p) {  // p = rhalf (64-row sub-block of wave's half)
      bf16x8_t af[4][2], bfr[2][2];
#pragma unroll
      for (int rf = 0; rf < 4; ++rf) {
        const int r = wm * 128 + p * 64 + rf * 16 + lrow;
#pragma unroll
        for (int ks = 0; ks < 2; ++ks)
          af[rf][ks] = *(const bf16x8_t*)(lA + r * 64 + (((ks * 4 + quad) ^ (r & 7)) << 3));
      }
#pragma unroll
      for (int cf = 0; cf < 2; ++cf) {
        const int c = wn * 32 + cf * 16 + lrow;
#pragma unroll
        for (int ks = 0; ks < 2; ++ks)
          bfr[cf][ks] = *(const bf16x8_t*)(lB + c * 64 + (((ks * 4 + quad) ^ (c & 7)) << 3));
      }
      if (p == 0 && t + 2 < nkt) STAGE(slot2, t + 2);
      __builtin_amdgcn_s_setprio(1);
#pragma unroll
      for (int rf = 0; rf < 4; ++rf)
#pragma unroll
        for (int cf = 0; cf < 2; ++cf)
#pragma unroll
          for (int ks = 0; ks < 2; ++ks)
            acc[p * 4 + rf][cf] = __builtin_amdgcn_mfma_f32_16x16x32_bf16(
                af[rf][ks], bfr[cf][ks], acc[p * 4 + rf][cf], 0, 0, 0);
      __builtin_amdgcn_s_setprio(0);
      if (p == 0) {
        __builtin_amdgcn_sched_barrier(0);
        __builtin_amdgcn_s_barrier();  // phase lockstep; no counter drain
        __builtin_amdgcn_sched_barrier(0);
      }
    }
    // Tile boundary: wait tile t+1's stages (counted), publish its slot.
    __builtin_amdgcn_sched_barrier(0);
    if (t + 1 < nkt) {
      if (t + 2 < nkt)
        asm volatile("s_waitcnt vmcnt(6)" ::: "memory");
      else
        asm volatile("s_waitcnt vmcnt(0)" ::: "memory");
      __builtin_amdgcn_s_barrier();
      __builtin_amdgcn_sched_barrier(0);
    }
    slot = (slot == 2) ? 0 : slot + 1;
  }

  // Epilogue: C/D frag layout col=lane&15, row=(lane>>4)*4+reg.
#pragma unroll
  for (int i = 0; i < 8; ++i) {
    const int rbase = row0 + wm * 128 + (i >> 2) * 64 + (i & 3) * 16 + quad * 4;
#pragma unroll
    for (int j = 0; j < 2; ++j) {
      const int c = col0 + wn * 32 + j * 16 + lrow;
#pragma unroll
      for (int r = 0; r < 4; ++r) C[(size_t)(rbase + r) * ldc + c] = acc[i][j][r];
    }
  }
}

// =========================================================================
// GEMM1 fast (t2-tier fallback): energy = Eh*Fh^T + Eh*Fl^T + El*Fh^T.
// =========================================================================
__global__ __launch_bounds__(256) void gemm1_fast(const __bf16* __restrict__ Eh,
                                                  const __bf16* __restrict__ El,
                                                  const __bf16* __restrict__ Fh,
                                                  const __bf16* __restrict__ Fl,
                                                  float* __restrict__ C,
                                                  int row_base) {
  __shared__ __bf16 sAh[BM * BK], sAl[BM * BK], sBh[BN * BK], sBl[BN * BK];
  const int tid = threadIdx.x;
  const int wave = tid >> 6, lane = tid & 63;
  const int row0 = row_base + blockIdx.x * BM, col0 = blockIdx.y * BN;
  const int wm = wave >> 1, wn = wave & 1;
  const int lrow = lane & 15, quad = lane >> 4;

  f32x4_t acc[4][4];
#pragma unroll
  for (int i = 0; i < 4; i++)
#pragma unroll
    for (int j = 0; j < 4; j++) acc[i][j] = (f32x4_t){0.f, 0.f, 0.f, 0.f};

  for (int k0 = 0; k0 < D_DIM; k0 += BK) {
#pragma unroll
    for (int r = 0; r < 2; r++) {
      int c = (r * 4 + wave) * 64 + lane;
      int row = c >> 2;
      int ko = (c & 3) << 3;
      size_t ga = (size_t)(row0 + row) * D_DIM + k0 + ko;
      size_t gb = (size_t)(col0 + row) * D_DIM + k0 + ko;
      gload_lds16(Eh + ga, sAh + c * 8);
      gload_lds16(El + ga, sAl + c * 8);
      gload_lds16(Fh + gb, sBh + c * 8);
      gload_lds16(Fl + gb, sBl + c * 8);
    }
    __syncthreads();

    bf16x8_t ah[4], al[4], bh[4], bl[4];
#pragma unroll
    for (int i = 0; i < 4; i++) {
      int ra = (wm * 64 + i * 16 + lrow) * BK + quad * 8;
      ah[i] = *(const bf16x8_t*)(sAh + ra);
      al[i] = *(const bf16x8_t*)(sAl + ra);
      int rb = (wn * 64 + i * 16 + lrow) * BK + quad * 8;
      bh[i] = *(const bf16x8_t*)(sBh + rb);
      bl[i] = *(const bf16x8_t*)(sBl + rb);
    }
#pragma unroll
    for (int i = 0; i < 4; i++)
#pragma unroll
      for (int j = 0; j < 4; j++) {
        acc[i][j] = __builtin_amdgcn_mfma_f32_16x16x32_bf16(ah[i], bh[j], acc[i][j], 0, 0, 0);
        acc[i][j] = __builtin_amdgcn_mfma_f32_16x16x32_bf16(ah[i], bl[j], acc[i][j], 0, 0, 0);
        acc[i][j] = __builtin_amdgcn_mfma_f32_16x16x32_bf16(al[i], bh[j], acc[i][j], 0, 0, 0);
      }
    __syncthreads();
  }

#pragma unroll
  for (int i = 0; i < 4; i++) {
    int rbase = row0 + wm * 64 + i * 16 + quad * 4;
#pragma unroll
    for (int j = 0; j < 4; j++) {
      int c = col0 + wn * 64 + j * 16 + lrow;
#pragma unroll
      for (int r = 0; r < 4; r++) C[(size_t)(rbase + r) * M_FACTS + c] = acc[i][j][r];
    }
  }
}

// =========================================================================
// GEMM2 register-staged double buffer (t2-tier fallback).
// =========================================================================
__global__ __launch_bounds__(256) void gemm2_reg(const __bf16* __restrict__ Wb,
                                                 const __bf16* __restrict__ Ft,
                                                 float* __restrict__ O,
                                                 int out_row0) {
  __shared__ __bf16 sW[2][BM * BK];
  __shared__ __bf16 sF[2][BN * BK];
  const int tid = threadIdx.x;
  const int wave = tid >> 6, lane = tid & 63;
  const int row0 = blockIdx.x * BM;
  const int col0 = blockIdx.y * BN;
  const int wm = wave >> 1, wn = wave & 1;
  const int lrow = lane & 15, quad = lane >> 4;

  const int id0 = wave * 64 + lane;
  const int r0 = id0 >> 2, c0 = (id0 & 3) << 3;
  const int id1 = id0 + 256;
  const int r1 = id1 >> 2, c1 = (id1 & 3) << 3;

  const __bf16* gW = Wb + (size_t)row0 * M_FACTS;
  const __bf16* gF = Ft + (size_t)col0 * M_FACTS;

  f32x4_t acc[4][4];
#pragma unroll
  for (int i = 0; i < 4; i++)
#pragma unroll
    for (int j = 0; j < 4; j++) acc[i][j] = (f32x4_t){0.f, 0.f, 0.f, 0.f};

  bf16x8_t rW0, rW1, rF0, rF1;
  rW0 = *(const bf16x8_t*)(gW + (size_t)r0 * M_FACTS + c0);
  rW1 = *(const bf16x8_t*)(gW + (size_t)r1 * M_FACTS + c1);
  rF0 = *(const bf16x8_t*)(gF + (size_t)r0 * M_FACTS + c0);
  rF1 = *(const bf16x8_t*)(gF + (size_t)r1 * M_FACTS + c1);
  *(bf16x8_t*)(&sW[0][id0 * 8]) = rW0;
  *(bf16x8_t*)(&sW[0][id1 * 8]) = rW1;
  *(bf16x8_t*)(&sF[0][id0 * 8]) = rF0;
  *(bf16x8_t*)(&sF[0][id1 * 8]) = rF1;
  rW0 = *(const bf16x8_t*)(gW + (size_t)r0 * M_FACTS + BK + c0);
  rW1 = *(const bf16x8_t*)(gW + (size_t)r1 * M_FACTS + BK + c1);
  rF0 = *(const bf16x8_t*)(gF + (size_t)r0 * M_FACTS + BK + c0);
  rF1 = *(const bf16x8_t*)(gF + (size_t)r1 * M_FACTS + BK + c1);
  __syncthreads();

  const int NT = M_FACTS / BK;
  for (int it = 0; it < NT; it++) {
    const int cur = it & 1;
    bf16x8_t a[4], b[4];
#pragma unroll
    for (int i = 0; i < 4; i++) {
      a[i] = *(const bf16x8_t*)(&sW[cur][(wm * 64 + i * 16 + lrow) * BK + quad * 8]);
      b[i] = *(const bf16x8_t*)(&sF[cur][(wn * 64 + i * 16 + lrow) * BK + quad * 8]);
    }
#pragma unroll
    for (int i = 0; i < 4; i++)
#pragma unroll
      for (int j = 0; j < 4; j++)
        acc[i][j] = __builtin_amdgcn_mfma_f32_16x16x32_bf16(a[i], b[j], acc[i][j], 0, 0, 0);

    __syncthreads();
    if (it + 1 < NT) {
      const int nxt = cur ^ 1;
      *(bf16x8_t*)(&sW[nxt][id0 * 8]) = rW0;
      *(bf16x8_t*)(&sW[nxt][id1 * 8]) = rW1;
      *(bf16x8_t*)(&sF[nxt][id0 * 8]) = rF0;
      *(bf16x8_t*)(&sF[nxt][id1 * 8]) = rF1;
      if (it + 2 < NT) {
        const int ko = (it + 2) * BK;
        rW0 = *(const bf16x8_t*)(gW + (size_t)r0 * M_FACTS + ko + c0);
        rW1 = *(const bf16x8_t*)(gW + (size_t)r1 * M_FACTS + ko + c1);
        rF0 = *(const bf16x8_t*)(gF + (size_t)r0 * M_FACTS + ko + c0);
        rF1 = *(const bf16x8_t*)(gF + (size_t)r1 * M_FACTS + ko + c1);
      }
      __syncthreads();
    }
  }

#pragma unroll
  for (int i = 0; i < 4; i++) {
    int rbase = out_row0 + row0 + wm * 64 + i * 16 + quad * 4;
#pragma unroll
    for (int j = 0; j < 4; j++) {
      int c = col0 + wn * 64 + j * 16 + lrow;
#pragma unroll
      for (int r = 0; r < 4; r++) O[(size_t)(rbase + r) * D_DIM + c] = acc[i][j][r];
    }
  }
}

// GEMM2 mid fallback: A = W fp32 (convert in staging), B = Ft via async.
__global__ __launch_bounds__(256) void gemm2_mid(const float* __restrict__ W,
                                                 const __bf16* __restrict__ Ft,
                                                 float* __restrict__ O) {
  __shared__ __bf16 sW[BM * BK], sF[BN * BK];
  const int tid = threadIdx.x;
  const int wave = tid >> 6, lane = tid & 63;
  const int row0 = blockIdx.x * BM, col0 = blockIdx.y * BN;
  const int wm = wave >> 1, wn = wave & 1;
  const int lrow = lane & 15, quad = lane >> 4;

  f32x4_t acc[4][4];
#pragma unroll
  for (int i = 0; i < 4; i++)
#pragma unroll
    for (int j = 0; j < 4; j++) acc[i][j] = (f32x4_t){0.f, 0.f, 0.f, 0.f};

  for (int k0 = 0; k0 < M_FACTS; k0 += BK) {
#pragma unroll
    for (int r = 0; r < 2; r++) {
      int c = (r * 4 + wave) * 64 + lane;
      int row = c >> 2;
      int ko = (c & 3) << 3;
      gload_lds16(Ft + (size_t)(col0 + row) * M_FACTS + k0 + ko, sF + c * 8);
    }
#pragma unroll
    for (int it = 0; it < 4; it++) {
      int flat = it * 256 + tid;
      int r = flat >> 3, q = flat & 7;
      float4 v = *(const float4*)(W + (size_t)(row0 + r) * M_FACTS + k0 + q * 4);
      bf16x4_t h;
      h[0] = (__bf16)v.x;
      h[1] = (__bf16)v.y;
      h[2] = (__bf16)v.z;
      h[3] = (__bf16)v.w;
      *(bf16x4_t*)(sW + r * BK + q * 4) = h;
    }
    __syncthreads();

    bf16x8_t a[4], b[4];
#pragma unroll
    for (int i = 0; i < 4; i++) {
      a[i] = *(const bf16x8_t*)(sW + (wm * 64 + i * 16 + lrow) * BK + quad * 8);
      b[i] = *(const bf16x8_t*)(sF + (wn * 64 + i * 16 + lrow) * BK + quad * 8);
    }
#pragma unroll
    for (int i = 0; i < 4; i++)
#pragma unroll
      for (int j = 0; j < 4; j++)
        acc[i][j] = __builtin_amdgcn_mfma_f32_16x16x32_bf16(a[i], b[j], acc[i][j], 0, 0, 0);
    __syncthreads();
  }

#pragma unroll
  for (int i = 0; i < 4; i++) {
    int rbase = row0 + wm * 64 + i * 16 + quad * 4;
#pragma unroll
    for (int j = 0; j < 4; j++) {
      int c = col0 + wn * 64 + j * 16 + lrow;
#pragma unroll
      for (int r = 0; r < 4; r++) O[(size_t)(rbase + r) * D_DIM + c] = acc[i][j][r];
    }
  }
}

// =========================================================================
// Softmax (optionally emitting bf16 copy of weights)
// =========================================================================
template <bool EMIT_BF16>
__global__ __launch_bounds__(256) void softmax_rows_t(float* __restrict__ W,
                                                      __bf16* __restrict__ Wb) {
  __shared__ float red[8];
  const int tid = threadIdx.x;
  float* p = W + (size_t)blockIdx.x * M_FACTS;

  float4 v[8];
  float mx = -3.4e38f;
#pragma unroll
  for (int i = 0; i < 8; i++) {
    v[i] = *(const float4*)(p + (size_t)(i * 256 + tid) * 4);
    mx = fmaxf(mx, fmaxf(fmaxf(v[i].x, v[i].y), fmaxf(v[i].z, v[i].w)));
  }
#pragma unroll
  for (int off = 32; off >= 1; off >>= 1) mx = fmaxf(mx, __shfl_xor(mx, off));
  const int wave = tid >> 6, lane = tid & 63;
  if (lane == 0) red[wave] = mx;
  __syncthreads();
  mx = fmaxf(fmaxf(red[0], red[1]), fmaxf(red[2], red[3]));

  float s = 0.f;
#pragma unroll
  for (int i = 0; i < 8; i++) {
    v[i].x = __expf(v[i].x - mx);
    v[i].y = __expf(v[i].y - mx);
    v[i].z = __expf(v[i].z - mx);
    v[i].w = __expf(v[i].w - mx);
    s += v[i].x + v[i].y + v[i].z + v[i].w;
  }
#pragma unroll
  for (int off = 32; off >= 1; off >>= 1) s += __shfl_xor(s, off);
  if (lane == 0) red[4 + wave] = s;
  __syncthreads();
  s = red[4] + red[5] + red[6] + red[7];
  float inv = 1.0f / s;
  __bf16* pb = EMIT_BF16 ? (Wb + (size_t)blockIdx.x * M_FACTS) : nullptr;
#pragma unroll
  for (int i = 0; i < 8; i++) {
    v[i].x *= inv;
    v[i].y *= inv;
    v[i].z *= inv;
    v[i].w *= inv;
    *(float4*)(p + (size_t)(i * 256 + tid) * 4) = v[i];
    if (EMIT_BF16) {
      bf16x4_t h;
      h[0] = (__bf16)v[i].x;
      h[1] = (__bf16)v[i].y;
      h[2] = (__bf16)v[i].z;
      h[3] = (__bf16)v[i].w;
      *(bf16x4_t*)(pb + (size_t)(i * 256 + tid) * 4) = h;
    }
  }
}

// =========================================================================
// Lowest-tier fallback kernels (ws < 80 MiB)
// =========================================================================
__global__ __launch_bounds__(256) void gemm1_energy(const float* __restrict__ A,
                                                    const float* __restrict__ B,
                                                    float* __restrict__ C) {
  __shared__ __align__(16) __bf16 sAh[BM * PADK];
  __shared__ __align__(16) __bf16 sAl[BM * PADK];
  __shared__ __align__(16) __bf16 sBh[BN * PADK];
  __shared__ __align__(16) __bf16 sBl[BN * PADK];

  const int tid = threadIdx.x;
  const int row0 = blockIdx.x * BM, col0 = blockIdx.y * BN;
  const int wave = tid >> 6, lane = tid & 63;
  const int wm = wave >> 1, wn = wave & 1;
  const int lrow = lane & 15, quad = lane >> 4;

  f32x4_t acc[4][4];
#pragma unroll
  for (int i = 0; i < 4; i++)
#pragma unroll
    for (int j = 0; j < 4; j++) acc[i][j] = (f32x4_t){0.f, 0.f, 0.f, 0.f};

  for (int k0 = 0; k0 < D_DIM; k0 += BK) {
    __syncthreads();
#pragma unroll
    for (int it = 0; it < 4; it++) {
      int flat = it * 256 + tid;
      int r = flat >> 3, kq = flat & 7;
      float4 va = *(const float4*)(A + (size_t)(row0 + r) * D_DIM + k0 + kq * 4);
      float4 vb = *(const float4*)(B + (size_t)(col0 + r) * D_DIM + k0 + kq * 4);
      float fa[4] = {va.x, va.y, va.z, va.w};
      float fb[4] = {vb.x, vb.y, vb.z, vb.w};
      bf16x4_t ah, al, bh, bl;
#pragma unroll
      for (int q = 0; q < 4; q++) {
        __bf16 h = (__bf16)fa[q];
        ah[q] = h;
        al[q] = (__bf16)(fa[q] - (float)h);
        __bf16 g = (__bf16)fb[q];
        bh[q] = g;
        bl[q] = (__bf16)(fb[q] - (float)g);
      }
      *(bf16x4_t*)(sAh + r * PADK + kq * 4) = ah;
      *(bf16x4_t*)(sAl + r * PADK + kq * 4) = al;
      *(bf16x4_t*)(sBh + r * PADK + kq * 4) = bh;
      *(bf16x4_t*)(sBl + r * PADK + kq * 4) = bl;
    }
    __syncthreads();

    bf16x8_t a_h[4], a_l[4], b_h[4], b_l[4];
#pragma unroll
    for (int i = 0; i < 4; i++) {
      int ra = wm * 64 + i * 16 + lrow;
      a_h[i] = *(const bf16x8_t*)(sAh + ra * PADK + quad * 8);
      a_l[i] = *(const bf16x8_t*)(sAl + ra * PADK + quad * 8);
      int rb = wn * 64 + i * 16 + lrow;
      b_h[i] = *(const bf16x8_t*)(sBh + rb * PADK + quad * 8);
      b_l[i] = *(const bf16x8_t*)(sBl + rb * PADK + quad * 8);
    }
#pragma unroll
    for (int i = 0; i < 4; i++)
#pragma unroll
      for (int j = 0; j < 4; j++) {
        acc[i][j] = __builtin_amdgcn_mfma_f32_16x16x32_bf16(a_h[i], b_h[j], acc[i][j], 0, 0, 0);
        acc[i][j] = __builtin_amdgcn_mfma_f32_16x16x32_bf16(a_h[i], b_l[j], acc[i][j], 0, 0, 0);
        acc[i][j] = __builtin_amdgcn_mfma_f32_16x16x32_bf16(a_l[i], b_h[j], acc[i][j], 0, 0, 0);
      }
  }

#pragma unroll
  for (int i = 0; i < 4; i++) {
    int rbase = row0 + wm * 64 + i * 16 + quad * 4;
#pragma unroll
    for (int j = 0; j < 4; j++) {
      int c = col0 + wn * 64 + j * 16 + lrow;
#pragma unroll
      for (int r = 0; r < 4; r++) C[(size_t)(rbase + r) * M_FACTS + c] = acc[i][j][r];
    }
  }
}

__global__ __launch_bounds__(256) void gemm2_out(const float* __restrict__ W,
                                                 const float* __restrict__ F,
                                                 float* __restrict__ O) {
  __shared__ __align__(16) __bf16 sW[BM * PADK];
  __shared__ __align__(16) __bf16 sFt[BN * PADK];

  const int tid = threadIdx.x;
  const int row0 = blockIdx.x * BM, col0 = blockIdx.y * BN;
  const int wave = tid >> 6, lane = tid & 63;
  const int wm = wave >> 1, wn = wave & 1;
  const int lrow = lane & 15, quad = lane >> 4;

  f32x4_t acc[4][4];
#pragma unroll
  for (int i = 0; i < 4; i++)
#pragma unroll
    for (int j = 0; j < 4; j++) acc[i][j] = (f32x4_t){0.f, 0.f, 0.f, 0.f};

  for (int k0 = 0; k0 < M_FACTS; k0 += BK) {
    __syncthreads();
#pragma unroll
    for (int it = 0; it < 4; it++) {
      int flat = it * 256 + tid;
      int r = flat >> 3, kq = flat & 7;
      float4 v = *(const float4*)(W + (size_t)(row0 + r) * M_FACTS + k0 + kq * 4);
      bf16x4_t h;
      h[0] = (__bf16)v.x;
      h[1] = (__bf16)v.y;
      h[2] = (__bf16)v.z;
      h[3] = (__bf16)v.w;
      *(bf16x4_t*)(sW + r * PADK + kq * 4) = h;
    }
#pragma unroll
    for (int it = 0; it < 4; it++) {
      int flat = it * 256 + tid;
      int m = flat >> 5, dq = flat & 31;
      float4 v = *(const float4*)(F + (size_t)(k0 + m) * D_DIM + col0 + dq * 4);
      sFt[(dq * 4 + 0) * PADK + m] = (__bf16)v.x;
      sFt[(dq * 4 + 1) * PADK + m] = (__bf16)v.y;
      sFt[(dq * 4 + 2) * PADK + m] = (__bf16)v.z;
      sFt[(dq * 4 + 3) * PADK + m] = (__bf16)v.w;
    }
    __syncthreads();

    bf16x8_t a[4], b[4];
#pragma unroll
    for (int i = 0; i < 4; i++) {
      a[i] = *(const bf16x8_t*)(sW + (wm * 64 + i * 16 + lrow) * PADK + quad * 8);
      b[i] = *(const bf16x8_t*)(sFt + (wn * 64 + i * 16 + lrow) * PADK + quad * 8);
    }
#pragma unroll
    for (int i = 0; i < 4; i++)
#pragma unroll
      for (int j = 0; j < 4; j++)
        acc[i][j] = __builtin_amdgcn_mfma_f32_16x16x32_bf16(a[i], b[j], acc[i][j], 0, 0, 0);
  }

#pragma unroll
  for (int i = 0; i < 4; i++) {
    int rbase = row0 + wm * 64 + i * 16 + quad * 4;
#pragma unroll
    for (int j = 0; j < 4; j++) {
      int c = col0 + wn * 64 + j * 16 + lrow;
#pragma unroll
      for (int r = 0; r < 4; r++) O[(size_t)(rbase + r) * D_DIM + c] = acc[i][j][r];
    }
  }
}

// =========================================================================
extern "C" void kernel_launch(void* const* d_in, const int* in_sizes, int n_in,
                              void* d_out, int out_size, void* d_ws, size_t ws_size,
                              hipStream_t stream) {
  const float* E = (const float*)d_in[0];  // [N, D]
  const float* F = (const float*)d_in[1];  // [M, D]
  float* outputs = (float*)d_out;                           // [N, D]
  float* weights = (float*)d_out + (size_t)N_ROWS * D_DIM;  // [N, M]

  const size_t MB = 1ull << 20;
  char* ws = (char*)d_ws;

  const bool t1 = ws_size >= 144 * MB;
  const bool t2 = !t1 && ws_size >= 80 * MB;
  const bool hasFtOnly = !t1 && !t2 && ws_size >= 16 * MB;

  if (t1) {
    // Layout: Ft 0-16MB | A2 16-64MB | B2 64-112MB | Wb 16-144MB (aliases
    // dead A2/B2 after gemm1).
    __bf16* Ft = (__bf16*)(ws + 0 * MB);
    __bf16* A2 = (__bf16*)(ws + 16 * MB);
    __bf16* B2 = (__bf16*)(ws + 64 * MB);
    __bf16* Wb = (__bf16*)(ws + 16 * MB);

    transpose_f_bf16<<<dim3(M_FACTS / 64, D_DIM / 64), 256, 0, stream>>>(F, Ft);
    split_concat_E<<<dim3((N_ROWS * D_DIM) / 1024), 256, 0, stream>>>(E, A2);
    split_concat_F<<<dim3((M_FACTS * D_DIM) / 1024), 256, 0, stream>>>(F, B2);

    // gemm1: ONE bf16 GEMM with K=3072 (ring kernel, counted vmcnt).
    // Grid (32,64): id%8 = x%8 -> all 64 col-blocks of an A-panel co-XCD.
    gemm_ring<<<dim3(N_ROWS / 256, M_FACTS / 128), 512, 0, stream>>>(
        A2, B2, weights, 3072, 3072, 3072, M_FACTS);

    softmax_rows_t<true><<<dim3(N_ROWS), 256, 0, stream>>>(weights, Wb);

    // gemm2: no split-K, no atomics. Grid (32,8) = 256 blocks = 1/CU.
    gemm_ring<<<dim3(N_ROWS / 256, D_DIM / 128), 512, 0, stream>>>(
        Wb, Ft, outputs, M_FACTS, M_FACTS, M_FACTS, D_DIM);
  } else if (t2) {
    __bf16* Ft = (__bf16*)(ws + 0 * MB);
    __bf16* Eh = (__bf16*)(ws + 16 * MB);
    __bf16* El = (__bf16*)(ws + 32 * MB);
    __bf16* Fh = (__bf16*)(ws + 48 * MB);
    __bf16* Fl = (__bf16*)(ws + 64 * MB);
    __bf16* Wb = (__bf16*)(ws + 16 * MB);

    transpose_f_bf16<<<dim3(M_FACTS / 64, D_DIM / 64), 256, 0, stream>>>(F, Ft);
    split_hi_lo<<<dim3((N_ROWS * D_DIM) / 1024), 256, 0, stream>>>(E, Eh, El);
    split_hi_lo<<<dim3((M_FACTS * D_DIM) / 1024), 256, 0, stream>>>(F, Fh, Fl);
    gemm1_fast<<<dim3(N_ROWS / BM, M_FACTS / BN), 256, 0, stream>>>(Eh, El, Fh, Fl,
                                                                    weights, 0);
    const int HALF = N_ROWS / 2;
    for (int h = 0; h < 2; h++) {
      float* Wchunk = weights + (size_t)h * HALF * M_FACTS;
      softmax_rows_t<true><<<dim3(HALF), 256, 0, stream>>>(Wchunk, Wb);
      gemm2_reg<<<dim3(HALF / BM, D_DIM / BN), 256, 0, stream>>>(Wb, Ft, outputs, h * HALF);
    }
  } else {
    __bf16* Ft = (__bf16*)ws;  // 16 MiB
    if (hasFtOnly) {
      transpose_f_bf16<<<dim3(M_FACTS / 64, D_DIM / 64), 256, 0, stream>>>(F, Ft);
    }
    gemm1_energy<<<dim3(N_ROWS / BM, M_FACTS / BN), 256, 0, stream>>>(E, F, weights);
    softmax_rows_t<false><<<dim3(N_ROWS), 256, 0, stream>>>(weights, nullptr);
    if (hasFtOnly) {
      gemm2_mid<<<dim3(N_ROWS / BM, D_DIM / BN), 256, 0, stream>>>(weights, Ft, outputs);
    } else {
      gemm2_out<<<dim3(N_ROWS / BM, D_DIM / BN), 256, 0, stream>>>(weights, F, outputs);
    }
  }
}

// Round 4
// 944.497 us; speedup vs baseline: 1.0197x; 1.0197x over previous
//
#include <hip/hip_runtime.h>
#include <hip/hip_bf16.h>
#include <math.h>
#include <stdint.h>

#define N_ROWS 8192
#define M_FACTS 8192
#define D_DIM 1024

typedef __bf16 bf16x8_t __attribute__((ext_vector_type(8)));
typedef __bf16 bf16x4_t __attribute__((ext_vector_type(4)));
typedef float f32x4_t __attribute__((ext_vector_type(4)));

#define BM 128
#define BN 128
#define BK 32
#define PADK 40  // legacy padded stride for fallback kernels

// Async global->LDS, 16B per lane. LDS dest = wave-uniform base + lane*16.
__device__ __forceinline__ void gload_lds16(const void* g, void* lds) {
  __builtin_amdgcn_global_load_lds(
      (__attribute__((address_space(1))) void*)(uintptr_t)g,
      (__attribute__((address_space(3))) void*)(uint32_t)(uintptr_t)lds,
      16, 0, 0);
}

// =========================================================================
// Precompute kernels
// =========================================================================

__global__ __launch_bounds__(256) void split_hi_lo(const float* __restrict__ X,
                                                   __bf16* __restrict__ H,
                                                   __bf16* __restrict__ L) {
  int i = blockIdx.x * 256 + threadIdx.x;
  float4 v = ((const float4*)X)[i];
  float f[4] = {v.x, v.y, v.z, v.w};
  bf16x4_t h, l;
#pragma unroll
  for (int q = 0; q < 4; q++) {
    __bf16 hh = (__bf16)f[q];
    h[q] = hh;
    l[q] = (__bf16)(f[q] - (float)hh);
  }
  ((bf16x4_t*)H)[i] = h;
  ((bf16x4_t*)L)[i] = l;
}

// E [N][1024] fp32 -> A2 [N][3072] bf16 = [Eh | El | Eh] (K-concat: the
// 3-product compensated GEMM becomes ONE standard bf16 GEMM with K=3072).
__global__ __launch_bounds__(256) void split_concat_E(const float* __restrict__ X,
                                                      __bf16* __restrict__ A2) {
  int idx = blockIdx.x * 256 + threadIdx.x;  // float4 index over N*1024/4
  int n = idx >> 8, d4 = idx & 255;
  float4 v = ((const float4*)X)[idx];
  float f[4] = {v.x, v.y, v.z, v.w};
  bf16x4_t h, l;
#pragma unroll
  for (int q = 0; q < 4; q++) {
    __bf16 hh = (__bf16)f[q];
    h[q] = hh;
    l[q] = (__bf16)(f[q] - (float)hh);
  }
  size_t base = (size_t)n * 3072 + d4 * 4;
  *(bf16x4_t*)(A2 + base) = h;
  *(bf16x4_t*)(A2 + base + 1024) = l;
  *(bf16x4_t*)(A2 + base + 2048) = h;
}

// F [M][1024] fp32 -> B2 [M][3072] bf16 = [Fh | Fh | Fl].
__global__ __launch_bounds__(256) void split_concat_F(const float* __restrict__ X,
                                                      __bf16* __restrict__ B2) {
  int idx = blockIdx.x * 256 + threadIdx.x;
  int m = idx >> 8, d4 = idx & 255;
  float4 v = ((const float4*)X)[idx];
  float f[4] = {v.x, v.y, v.z, v.w};
  bf16x4_t h, l;
#pragma unroll
  for (int q = 0; q < 4; q++) {
    __bf16 hh = (__bf16)f[q];
    h[q] = hh;
    l[q] = (__bf16)(f[q] - (float)hh);
  }
  size_t base = (size_t)m * 3072 + d4 * 4;
  *(bf16x4_t*)(B2 + base) = h;
  *(bf16x4_t*)(B2 + base + 1024) = h;
  *(bf16x4_t*)(B2 + base + 2048) = l;
}

// F fp32 [M][D] -> Ft bf16 [D][M]. 64x64 tiles; fp32 LDS tile stride 69.
__global__ __launch_bounds__(256) void transpose_f_bf16(const float* __restrict__ F,
                                                        __bf16* __restrict__ Ft) {
  __shared__ float t[64 * 69];
  const int tid = threadIdx.x;
  const int m0 = blockIdx.x * 64, d0 = blockIdx.y * 64;
#pragma unroll
  for (int p = 0; p < 4; p++) {
    int flat = p * 256 + tid;
    int m = flat >> 4, dq = flat & 15;
    float4 v = *(const float4*)(F + (size_t)(m0 + m) * D_DIM + d0 + dq * 4);
    t[(dq * 4 + 0) * 69 + m] = v.x;
    t[(dq * 4 + 1) * 69 + m] = v.y;
    t[(dq * 4 + 2) * 69 + m] = v.z;
    t[(dq * 4 + 3) * 69 + m] = v.w;
  }
  __syncthreads();
#pragma unroll
  for (int q = 0; q < 2; q++) {
    int id = q * 256 + tid;
    int d = id >> 3, c = id & 7;
    const float* row = t + d * 69 + c * 8;
    bf16x8_t o;
#pragma unroll
    for (int i = 0; i < 8; i++) o[i] = (__bf16)row[i];
    *(bf16x8_t*)(Ft + (size_t)(d0 + d) * M_FACTS + m0 + c * 8) = o;
  }
}

// =========================================================================
// Read-once double-buffered B^T GEMM:  C = A[*][K] * B[*][K]^T.
// RH=2: BM=256; RH=1: BM=128. BN=256, BK=64. 512 thr = 8 waves (2M x 4N),
// per-wave C = (RH*64) x 64.
//
// Resource arithmetic (per K-tile, per CU, RH=2):
//   MFMA floor = 256*256*64*2 / 4070 FLOP/cyc ~ 2060 cyc
//   LDS reads  = 8 waves * (8 B-frag + 16 A-frag) * 1KB = 192KB ~ 1536 cyc
//   -> MFMA-bound (round-3 ring was LDS-bound: phase scheme re-read frags).
// Each fragment is read from LDS EXACTLY ONCE per tile: B-frags held in
// registers across both row-halves; A-frags read per half. ~215 VGPR.
//
// Pipeline: 2 LDS slots; tile t+1 staged (gload_lds) at the START of tile
// t's compute; single vmcnt(0)+s_barrier at tile end. Issue-to-wait
// distance ~ 1 full tile (>=2000 cyc) >> 900-cyc HBM latency, and nothing
// newer is in flight at the wait, so vmcnt(0) == the counted wait.
// Exactly ONE barrier per K-tile (no __syncthreads in the loop).
// WAR: t's stages hit slot cur^1, whose tile-(t-1) reads finished before
// the previous boundary barrier. RAW: vmcnt(0)+barrier publishes cur^1.
// Swizzle (T2): LDS[row][q] = G[row][q ^ (row&7)] via pre-swizzled global
// source (linear LDS dest); ds_read applies the same XOR (involution).
// Measured 0 bank conflicts with this scheme (round 2/3).
// =========================================================================
template <int RH>
__global__ __launch_bounds__(512, 2) void gemm_big(const __bf16* __restrict__ A,
                                                   const __bf16* __restrict__ B,
                                                   float* __restrict__ C,
                                                   int K, int lda, int ldb, int ldc) {
  constexpr int BMT = RH * 128;
  __shared__ __align__(16) __bf16 sA[2][BMT * 64];
  __shared__ __align__(16) __bf16 sB[2][256 * 64];
  const int tid = threadIdx.x;  // 0..511
  const int wave = tid >> 6, lane = tid & 63;
  const int wm = wave >> 2;   // 0..1  (A half: rows wm*(RH*64))
  const int wn = wave & 3;    // 0..3  (C cols wn*64..+63)
  const int lrow = lane & 15, quad = lane >> 4;
  const int row0 = blockIdx.x * BMT;
  const int col0 = blockIdx.y * 256;

  // Staging (16B granules, linear LDS dest, pre-swizzled global source).
  // A: BMT*8 granules (RH*2 per thread); B: 256*8 = 2048 (4 per thread).
  auto STAGE = [&](int buf, int kt) {
    const int ko = kt * 64;
#pragma unroll
    for (int k = 0; k < RH * 2; k++) {
      int g = tid + 512 * k;
      int sr = g >> 3;
      int so = ((g & 7) ^ (sr & 7)) << 3;
      gload_lds16(A + (size_t)(row0 + sr) * lda + ko + so, &sA[buf][g * 8]);
    }
#pragma unroll
    for (int k = 0; k < 4; k++) {
      int g = tid + 512 * k;
      int sr = g >> 3;
      int so = ((g & 7) ^ (sr & 7)) << 3;
      gload_lds16(B + (size_t)(col0 + sr) * ldb + ko + so, &sB[buf][g * 8]);
    }
  };

  f32x4_t acc[RH * 4][4];
#pragma unroll
  for (int i = 0; i < RH * 4; i++)
#pragma unroll
    for (int j = 0; j < 4; j++) acc[i][j] = (f32x4_t){0.f, 0.f, 0.f, 0.f};

  const int nkt = K >> 6;

  // Prologue: stage tile 0 -> slot 0, publish.
  STAGE(0, 0);
  asm volatile("s_waitcnt vmcnt(0)" ::: "memory");
  __builtin_amdgcn_s_barrier();
  __builtin_amdgcn_sched_barrier(0);

  for (int t = 0; t < nkt; ++t) {
    const int cur = t & 1;
    const __bf16* lA = &sA[cur][0];
    const __bf16* lB = &sB[cur][0];

    // ---- issue next tile's stages FIRST (maximum latency cover)
    if (t + 1 < nkt) STAGE(cur ^ 1, t + 1);
    __builtin_amdgcn_sched_barrier(0);  // pin stages before the ds_reads

    // ---- B fragments: read ONCE, held for the whole tile
    bf16x8_t bfr[4][2];
#pragma unroll
    for (int cf = 0; cf < 4; ++cf) {
      const int c = wn * 64 + cf * 16 + lrow;
#pragma unroll
      for (int ks = 0; ks < 2; ++ks)
        bfr[cf][ks] = *(const bf16x8_t*)(lB + c * 64 + (((ks * 4 + quad) ^ (c & 7)) << 3));
    }
    // ---- row-halves: A fragments read once each, 32 MFMA per half
#pragma unroll
    for (int rh = 0; rh < RH; ++rh) {
      bf16x8_t af[4][2];
#pragma unroll
      for (int rf = 0; rf < 4; ++rf) {
        const int r = wm * (RH * 64) + rh * 64 + rf * 16 + lrow;
#pragma unroll
        for (int ks = 0; ks < 2; ++ks)
          af[rf][ks] = *(const bf16x8_t*)(lA + r * 64 + (((ks * 4 + quad) ^ (r & 7)) << 3));
      }
      __builtin_amdgcn_s_setprio(1);
#pragma unroll
      for (int rf = 0; rf < 4; ++rf)
#pragma unroll
        for (int cf = 0; cf < 4; ++cf)
#pragma unroll
          for (int ks = 0; ks < 2; ++ks)
            acc[rh * 4 + rf][cf] = __builtin_amdgcn_mfma_f32_16x16x32_bf16(
                af[rf][ks], bfr[cf][ks], acc[rh * 4 + rf][cf], 0, 0, 0);
      __builtin_amdgcn_s_setprio(0);
    }

    // ---- tile boundary: only tile t+1's loads outstanding -> vmcnt(0)
    __builtin_amdgcn_sched_barrier(0);
    if (t + 1 < nkt) {
      asm volatile("s_waitcnt vmcnt(0)" ::: "memory");
      __builtin_amdgcn_s_barrier();
      __builtin_amdgcn_sched_barrier(0);
    }
  }

  // Epilogue: C/D frag layout col=lane&15, row=(lane>>4)*4+reg.
#pragma unroll
  for (int i = 0; i < RH * 4; ++i) {
    const int rbase = row0 + wm * (RH * 64) + (i >> 2) * 64 + (i & 3) * 16 + quad * 4;
#pragma unroll
    for (int j = 0; j < 4; ++j) {
      const int c = col0 + wn * 64 + j * 16 + lrow;
#pragma unroll
      for (int r = 0; r < 4; ++r) C[(size_t)(rbase + r) * ldc + c] = acc[i][j][r];
    }
  }
}

// =========================================================================
// GEMM1 fast (t2-tier fallback): energy = Eh*Fh^T + Eh*Fl^T + El*Fh^T.
// =========================================================================
__global__ __launch_bounds__(256) void gemm1_fast(const __bf16* __restrict__ Eh,
                                                  const __bf16* __restrict__ El,
                                                  const __bf16* __restrict__ Fh,
                                                  const __bf16* __restrict__ Fl,
                                                  float* __restrict__ C,
                                                  int row_base) {
  __shared__ __bf16 sAh[BM * BK], sAl[BM * BK], sBh[BN * BK], sBl[BN * BK];
  const int tid = threadIdx.x;
  const int wave = tid >> 6, lane = tid & 63;
  const int row0 = row_base + blockIdx.x * BM, col0 = blockIdx.y * BN;
  const int wm = wave >> 1, wn = wave & 1;
  const int lrow = lane & 15, quad = lane >> 4;

  f32x4_t acc[4][4];
#pragma unroll
  for (int i = 0; i < 4; i++)
#pragma unroll
    for (int j = 0; j < 4; j++) acc[i][j] = (f32x4_t){0.f, 0.f, 0.f, 0.f};

  for (int k0 = 0; k0 < D_DIM; k0 += BK) {
#pragma unroll
    for (int r = 0; r < 2; r++) {
      int c = (r * 4 + wave) * 64 + lane;
      int row = c >> 2;
      int ko = (c & 3) << 3;
      size_t ga = (size_t)(row0 + row) * D_DIM + k0 + ko;
      size_t gb = (size_t)(col0 + row) * D_DIM + k0 + ko;
      gload_lds16(Eh + ga, sAh + c * 8);
      gload_lds16(El + ga, sAl + c * 8);
      gload_lds16(Fh + gb, sBh + c * 8);
      gload_lds16(Fl + gb, sBl + c * 8);
    }
    __syncthreads();

    bf16x8_t ah[4], al[4], bh[4], bl[4];
#pragma unroll
    for (int i = 0; i < 4; i++) {
      int ra = (wm * 64 + i * 16 + lrow) * BK + quad * 8;
      ah[i] = *(const bf16x8_t*)(sAh + ra);
      al[i] = *(const bf16x8_t*)(sAl + ra);
      int rb = (wn * 64 + i * 16 + lrow) * BK + quad * 8;
      bh[i] = *(const bf16x8_t*)(sBh + rb);
      bl[i] = *(const bf16x8_t*)(sBl + rb);
    }
#pragma unroll
    for (int i = 0; i < 4; i++)
#pragma unroll
      for (int j = 0; j < 4; j++) {
        acc[i][j] = __builtin_amdgcn_mfma_f32_16x16x32_bf16(ah[i], bh[j], acc[i][j], 0, 0, 0);
        acc[i][j] = __builtin_amdgcn_mfma_f32_16x16x32_bf16(ah[i], bl[j], acc[i][j], 0, 0, 0);
        acc[i][j] = __builtin_amdgcn_mfma_f32_16x16x32_bf16(al[i], bh[j], acc[i][j], 0, 0, 0);
      }
    __syncthreads();
  }

#pragma unroll
  for (int i = 0; i < 4; i++) {
    int rbase = row0 + wm * 64 + i * 16 + quad * 4;
#pragma unroll
    for (int j = 0; j < 4; j++) {
      int c = col0 + wn * 64 + j * 16 + lrow;
#pragma unroll
      for (int r = 0; r < 4; r++) C[(size_t)(rbase + r) * M_FACTS + c] = acc[i][j][r];
    }
  }
}

// =========================================================================
// GEMM2 register-staged double buffer (t2-tier fallback).
// =========================================================================
__global__ __launch_bounds__(256) void gemm2_reg(const __bf16* __restrict__ Wb,
                                                 const __bf16* __restrict__ Ft,
                                                 float* __restrict__ O,
                                                 int out_row0) {
  __shared__ __bf16 sW[2][BM * BK];
  __shared__ __bf16 sF[2][BN * BK];
  const int tid = threadIdx.x;
  const int wave = tid >> 6, lane = tid & 63;
  const int row0 = blockIdx.x * BM;
  const int col0 = blockIdx.y * BN;
  const int wm = wave >> 1, wn = wave & 1;
  const int lrow = lane & 15, quad = lane >> 4;

  const int id0 = wave * 64 + lane;
  const int r0 = id0 >> 2, c0 = (id0 & 3) << 3;
  const int id1 = id0 + 256;
  const int r1 = id1 >> 2, c1 = (id1 & 3) << 3;

  const __bf16* gW = Wb + (size_t)row0 * M_FACTS;
  const __bf16* gF = Ft + (size_t)col0 * M_FACTS;

  f32x4_t acc[4][4];
#pragma unroll
  for (int i = 0; i < 4; i++)
#pragma unroll
    for (int j = 0; j < 4; j++) acc[i][j] = (f32x4_t){0.f, 0.f, 0.f, 0.f};

  bf16x8_t rW0, rW1, rF0, rF1;
  rW0 = *(const bf16x8_t*)(gW + (size_t)r0 * M_FACTS + c0);
  rW1 = *(const bf16x8_t*)(gW + (size_t)r1 * M_FACTS + c1);
  rF0 = *(const bf16x8_t*)(gF + (size_t)r0 * M_FACTS + c0);
  rF1 = *(const bf16x8_t*)(gF + (size_t)r1 * M_FACTS + c1);
  *(bf16x8_t*)(&sW[0][id0 * 8]) = rW0;
  *(bf16x8_t*)(&sW[0][id1 * 8]) = rW1;
  *(bf16x8_t*)(&sF[0][id0 * 8]) = rF0;
  *(bf16x8_t*)(&sF[0][id1 * 8]) = rF1;
  rW0 = *(const bf16x8_t*)(gW + (size_t)r0 * M_FACTS + BK + c0);
  rW1 = *(const bf16x8_t*)(gW + (size_t)r1 * M_FACTS + BK + c1);
  rF0 = *(const bf16x8_t*)(gF + (size_t)r0 * M_FACTS + BK + c0);
  rF1 = *(const bf16x8_t*)(gF + (size_t)r1 * M_FACTS + BK + c1);
  __syncthreads();

  const int NT = M_FACTS / BK;
  for (int it = 0; it < NT; it++) {
    const int cur = it & 1;
    bf16x8_t a[4], b[4];
#pragma unroll
    for (int i = 0; i < 4; i++) {
      a[i] = *(const bf16x8_t*)(&sW[cur][(wm * 64 + i * 16 + lrow) * BK + quad * 8]);
      b[i] = *(const bf16x8_t*)(&sF[cur][(wn * 64 + i * 16 + lrow) * BK + quad * 8]);
    }
#pragma unroll
    for (int i = 0; i < 4; i++)
#pragma unroll
      for (int j = 0; j < 4; j++)
        acc[i][j] = __builtin_amdgcn_mfma_f32_16x16x32_bf16(a[i], b[j], acc[i][j], 0, 0, 0);

    __syncthreads();
    if (it + 1 < NT) {
      const int nxt = cur ^ 1;
      *(bf16x8_t*)(&sW[nxt][id0 * 8]) = rW0;
      *(bf16x8_t*)(&sW[nxt][id1 * 8]) = rW1;
      *(bf16x8_t*)(&sF[nxt][id0 * 8]) = rF0;
      *(bf16x8_t*)(&sF[nxt][id1 * 8]) = rF1;
      if (it + 2 < NT) {
        const int ko = (it + 2) * BK;
        rW0 = *(const bf16x8_t*)(gW + (size_t)r0 * M_FACTS + ko + c0);
        rW1 = *(const bf16x8_t*)(gW + (size_t)r1 * M_FACTS + ko + c1);
        rF0 = *(const bf16x8_t*)(gF + (size_t)r0 * M_FACTS + ko + c0);
        rF1 = *(const bf16x8_t*)(gF + (size_t)r1 * M_FACTS + ko + c1);
      }
      __syncthreads();
    }
  }

#pragma unroll
  for (int i = 0; i < 4; i++) {
    int rbase = out_row0 + row0 + wm * 64 + i * 16 + quad * 4;
#pragma unroll
    for (int j = 0; j < 4; j++) {
      int c = col0 + wn * 64 + j * 16 + lrow;
#pragma unroll
      for (int r = 0; r < 4; r++) O[(size_t)(rbase + r) * D_DIM + c] = acc[i][j][r];
    }
  }
}

// GEMM2 mid fallback: A = W fp32 (convert in staging), B = Ft via async.
__global__ __launch_bounds__(256) void gemm2_mid(const float* __restrict__ W,
                                                 const __bf16* __restrict__ Ft,
                                                 float* __restrict__ O) {
  __shared__ __bf16 sW[BM * BK], sF[BN * BK];
  const int tid = threadIdx.x;
  const int wave = tid >> 6, lane = tid & 63;
  const int row0 = blockIdx.x * BM, col0 = blockIdx.y * BN;
  const int wm = wave >> 1, wn = wave & 1;
  const int lrow = lane & 15, quad = lane >> 4;

  f32x4_t acc[4][4];
#pragma unroll
  for (int i = 0; i < 4; i++)
#pragma unroll
    for (int j = 0; j < 4; j++) acc[i][j] = (f32x4_t){0.f, 0.f, 0.f, 0.f};

  for (int k0 = 0; k0 < M_FACTS; k0 += BK) {
#pragma unroll
    for (int r = 0; r < 2; r++) {
      int c = (r * 4 + wave) * 64 + lane;
      int row = c >> 2;
      int ko = (c & 3) << 3;
      gload_lds16(Ft + (size_t)(col0 + row) * M_FACTS + k0 + ko, sF + c * 8);
    }
#pragma unroll
    for (int it = 0; it < 4; it++) {
      int flat = it * 256 + tid;
      int r = flat >> 3, q = flat & 7;
      float4 v = *(const float4*)(W + (size_t)(row0 + r) * M_FACTS + k0 + q * 4);
      bf16x4_t h;
      h[0] = (__bf16)v.x;
      h[1] = (__bf16)v.y;
      h[2] = (__bf16)v.z;
      h[3] = (__bf16)v.w;
      *(bf16x4_t*)(sW + r * BK + q * 4) = h;
    }
    __syncthreads();

    bf16x8_t a[4], b[4];
#pragma unroll
    for (int i = 0; i < 4; i++) {
      a[i] = *(const bf16x8_t*)(sW + (wm * 64 + i * 16 + lrow) * BK + quad * 8);
      b[i] = *(const bf16x8_t*)(sF + (wn * 64 + i * 16 + lrow) * BK + quad * 8);
    }
#pragma unroll
    for (int i = 0; i < 4; i++)
#pragma unroll
      for (int j = 0; j < 4; j++)
        acc[i][j] = __builtin_amdgcn_mfma_f32_16x16x32_bf16(a[i], b[j], acc[i][j], 0, 0, 0);
    __syncthreads();
  }

#pragma unroll
  for (int i = 0; i < 4; i++) {
    int rbase = row0 + wm * 64 + i * 16 + quad * 4;
#pragma unroll
    for (int j = 0; j < 4; j++) {
      int c = col0 + wn * 64 + j * 16 + lrow;
#pragma unroll
      for (int r = 0; r < 4; r++) O[(size_t)(rbase + r) * D_DIM + c] = acc[i][j][r];
    }
  }
}

// =========================================================================
// Softmax (optionally emitting bf16 copy of weights)
// =========================================================================
template <bool EMIT_BF16>
__global__ __launch_bounds__(256) void softmax_rows_t(float* __restrict__ W,
                                                      __bf16* __restrict__ Wb) {
  __shared__ float red[8];
  const int tid = threadIdx.x;
  float* p = W + (size_t)blockIdx.x * M_FACTS;

  float4 v[8];
  float mx = -3.4e38f;
#pragma unroll
  for (int i = 0; i < 8; i++) {
    v[i] = *(const float4*)(p + (size_t)(i * 256 + tid) * 4);
    mx = fmaxf(mx, fmaxf(fmaxf(v[i].x, v[i].y), fmaxf(v[i].z, v[i].w)));
  }
#pragma unroll
  for (int off = 32; off >= 1; off >>= 1) mx = fmaxf(mx, __shfl_xor(mx, off));
  const int wave = tid >> 6, lane = tid & 63;
  if (lane == 0) red[wave] = mx;
  __syncthreads();
  mx = fmaxf(fmaxf(red[0], red[1]), fmaxf(red[2], red[3]));

  float s = 0.f;
#pragma unroll
  for (int i = 0; i < 8; i++) {
    v[i].x = __expf(v[i].x - mx);
    v[i].y = __expf(v[i].y - mx);
    v[i].z = __expf(v[i].z - mx);
    v[i].w = __expf(v[i].w - mx);
    s += v[i].x + v[i].y + v[i].z + v[i].w;
  }
#pragma unroll
  for (int off = 32; off >= 1; off >>= 1) s += __shfl_xor(s, off);
  if (lane == 0) red[4 + wave] = s;
  __syncthreads();
  s = red[4] + red[5] + red[6] + red[7];
  float inv = 1.0f / s;
  __bf16* pb = EMIT_BF16 ? (Wb + (size_t)blockIdx.x * M_FACTS) : nullptr;
#pragma unroll
  for (int i = 0; i < 8; i++) {
    v[i].x *= inv;
    v[i].y *= inv;
    v[i].z *= inv;
    v[i].w *= inv;
    *(float4*)(p + (size_t)(i * 256 + tid) * 4) = v[i];
    if (EMIT_BF16) {
      bf16x4_t h;
      h[0] = (__bf16)v[i].x;
      h[1] = (__bf16)v[i].y;
      h[2] = (__bf16)v[i].z;
      h[3] = (__bf16)v[i].w;
      *(bf16x4_t*)(pb + (size_t)(i * 256 + tid) * 4) = h;
    }
  }
}

// =========================================================================
// Lowest-tier fallback kernels (ws < 80 MiB)
// =========================================================================
__global__ __launch_bounds__(256) void gemm1_energy(const float* __restrict__ A,
                                                    const float* __restrict__ B,
                                                    float* __restrict__ C) {
  __shared__ __align__(16) __bf16 sAh[BM * PADK];
  __shared__ __align__(16) __bf16 sAl[BM * PADK];
  __shared__ __align__(16) __bf16 sBh[BN * PADK];
  __shared__ __align__(16) __bf16 sBl[BN * PADK];

  const int tid = threadIdx.x;
  const int row0 = blockIdx.x * BM, col0 = blockIdx.y * BN;
  const int wave = tid >> 6, lane = tid & 63;
  const int wm = wave >> 1, wn = wave & 1;
  const int lrow = lane & 15, quad = lane >> 4;

  f32x4_t acc[4][4];
#pragma unroll
  for (int i = 0; i < 4; i++)
#pragma unroll
    for (int j = 0; j < 4; j++) acc[i][j] = (f32x4_t){0.f, 0.f, 0.f, 0.f};

  for (int k0 = 0; k0 < D_DIM; k0 += BK) {
    __syncthreads();
#pragma unroll
    for (int it = 0; it < 4; it++) {
      int flat = it * 256 + tid;
      int r = flat >> 3, kq = flat & 7;
      float4 va = *(const float4*)(A + (size_t)(row0 + r) * D_DIM + k0 + kq * 4);
      float4 vb = *(const float4*)(B + (size_t)(col0 + r) * D_DIM + k0 + kq * 4);
      float fa[4] = {va.x, va.y, va.z, va.w};
      float fb[4] = {vb.x, vb.y, vb.z, vb.w};
      bf16x4_t ah, al, bh, bl;
#pragma unroll
      for (int q = 0; q < 4; q++) {
        __bf16 h = (__bf16)fa[q];
        ah[q] = h;
        al[q] = (__bf16)(fa[q] - (float)h);
        __bf16 g = (__bf16)fb[q];
        bh[q] = g;
        bl[q] = (__bf16)(fb[q] - (float)g);
      }
      *(bf16x4_t*)(sAh + r * PADK + kq * 4) = ah;
      *(bf16x4_t*)(sAl + r * PADK + kq * 4) = al;
      *(bf16x4_t*)(sBh + r * PADK + kq * 4) = bh;
      *(bf16x4_t*)(sBl + r * PADK + kq * 4) = bl;
    }
    __syncthreads();

    bf16x8_t a_h[4], a_l[4], b_h[4], b_l[4];
#pragma unroll
    for (int i = 0; i < 4; i++) {
      int ra = wm * 64 + i * 16 + lrow;
      a_h[i] = *(const bf16x8_t*)(sAh + ra * PADK + quad * 8);
      a_l[i] = *(const bf16x8_t*)(sAl + ra * PADK + quad * 8);
      int rb = wn * 64 + i * 16 + lrow;
      b_h[i] = *(const bf16x8_t*)(sBh + rb * PADK + quad * 8);
      b_l[i] = *(const bf16x8_t*)(sBl + rb * PADK + quad * 8);
    }
#pragma unroll
    for (int i = 0; i < 4; i++)
#pragma unroll
      for (int j = 0; j < 4; j++) {
        acc[i][j] = __builtin_amdgcn_mfma_f32_16x16x32_bf16(a_h[i], b_h[j], acc[i][j], 0, 0, 0);
        acc[i][j] = __builtin_amdgcn_mfma_f32_16x16x32_bf16(a_h[i], b_l[j], acc[i][j], 0, 0, 0);
        acc[i][j] = __builtin_amdgcn_mfma_f32_16x16x32_bf16(a_l[i], b_h[j], acc[i][j], 0, 0, 0);
      }
  }

#pragma unroll
  for (int i = 0; i < 4; i++) {
    int rbase = row0 + wm * 64 + i * 16 + quad * 4;
#pragma unroll
    for (int j = 0; j < 4; j++) {
      int c = col0 + wn * 64 + j * 16 + lrow;
#pragma unroll
      for (int r = 0; r < 4; r++) C[(size_t)(rbase + r) * M_FACTS + c] = acc[i][j][r];
    }
  }
}

__global__ __launch_bounds__(256) void gemm2_out(const float* __restrict__ W,
                                                 const float* __restrict__ F,
                                                 float* __restrict__ O) {
  __shared__ __align__(16) __bf16 sW[BM * PADK];
  __shared__ __align__(16) __bf16 sFt[BN * PADK];

  const int tid = threadIdx.x;
  const int row0 = blockIdx.x * BM, col0 = blockIdx.y * BN;
  const int wave = tid >> 6, lane = tid & 63;
  const int wm = wave >> 1, wn = wave & 1;
  const int lrow = lane & 15, quad = lane >> 4;

  f32x4_t acc[4][4];
#pragma unroll
  for (int i = 0; i < 4; i++)
#pragma unroll
    for (int j = 0; j < 4; j++) acc[i][j] = (f32x4_t){0.f, 0.f, 0.f, 0.f};

  for (int k0 = 0; k0 < M_FACTS; k0 += BK) {
    __syncthreads();
#pragma unroll
    for (int it = 0; it < 4; it++) {
      int flat = it * 256 + tid;
      int r = flat >> 3, kq = flat & 7;
      float4 v = *(const float4*)(W + (size_t)(row0 + r) * M_FACTS + k0 + kq * 4);
      bf16x4_t h;
      h[0] = (__bf16)v.x;
      h[1] = (__bf16)v.y;
      h[2] = (__bf16)v.z;
      h[3] = (__bf16)v.w;
      *(bf16x4_t*)(sW + r * PADK + kq * 4) = h;
    }
#pragma unroll
    for (int it = 0; it < 4; it++) {
      int flat = it * 256 + tid;
      int m = flat >> 5, dq = flat & 31;
      float4 v = *(const float4*)(F + (size_t)(k0 + m) * D_DIM + col0 + dq * 4);
      sFt[(dq * 4 + 0) * PADK + m] = (__bf16)v.x;
      sFt[(dq * 4 + 1) * PADK + m] = (__bf16)v.y;
      sFt[(dq * 4 + 2) * PADK + m] = (__bf16)v.z;
      sFt[(dq * 4 + 3) * PADK + m] = (__bf16)v.w;
    }
    __syncthreads();

    bf16x8_t a[4], b[4];
#pragma unroll
    for (int i = 0; i < 4; i++) {
      a[i] = *(const bf16x8_t*)(sW + (wm * 64 + i * 16 + lrow) * PADK + quad * 8);
      b[i] = *(const bf16x8_t*)(sFt + (wn * 64 + i * 16 + lrow) * PADK + quad * 8);
    }
#pragma unroll
    for (int i = 0; i < 4; i++)
#pragma unroll
      for (int j = 0; j < 4; j++)
        acc[i][j] = __builtin_amdgcn_mfma_f32_16x16x32_bf16(a[i], b[j], acc[i][j], 0, 0, 0);
  }

#pragma unroll
  for (int i = 0; i < 4; i++) {
    int rbase = row0 + wm * 64 + i * 16 + quad * 4;
#pragma unroll
    for (int j = 0; j < 4; j++) {
      int c = col0 + wn * 64 + j * 16 + lrow;
#pragma unroll
      for (int r = 0; r < 4; r++) O[(size_t)(rbase + r) * D_DIM + c] = acc[i][j][r];
    }
  }
}

// =========================================================================
extern "C" void kernel_launch(void* const* d_in, const int* in_sizes, int n_in,
                              void* d_out, int out_size, void* d_ws, size_t ws_size,
                              hipStream_t stream) {
  const float* E = (const float*)d_in[0];  // [N, D]
  const float* F = (const float*)d_in[1];  // [M, D]
  float* outputs = (float*)d_out;                           // [N, D]
  float* weights = (float*)d_out + (size_t)N_ROWS * D_DIM;  // [N, M]

  const size_t MB = 1ull << 20;
  char* ws = (char*)d_ws;

  const bool t1 = ws_size >= 144 * MB;
  const bool t2 = !t1 && ws_size >= 80 * MB;
  const bool hasFtOnly = !t1 && !t2 && ws_size >= 16 * MB;

  if (t1) {
    // Layout: Ft 0-16MB | A2 16-64MB | B2 64-112MB | Wb 16-144MB (aliases
    // dead A2/B2 after gemm1).
    __bf16* Ft = (__bf16*)(ws + 0 * MB);
    __bf16* A2 = (__bf16*)(ws + 16 * MB);
    __bf16* B2 = (__bf16*)(ws + 64 * MB);
    __bf16* Wb = (__bf16*)(ws + 16 * MB);

    transpose_f_bf16<<<dim3(M_FACTS / 64, D_DIM / 64), 256, 0, stream>>>(F, Ft);
    split_concat_E<<<dim3((N_ROWS * D_DIM) / 1024), 256, 0, stream>>>(E, A2);
    split_concat_F<<<dim3((M_FACTS * D_DIM) / 1024), 256, 0, stream>>>(F, B2);

    // gemm1: ONE bf16 GEMM, K=3072. Grid (32,32); id%8 = x%8 -> all 32
    // col-blocks of an A-panel co-XCD (panel 1.5MB fits XCD L2).
    gemm_big<2><<<dim3(N_ROWS / 256, M_FACTS / 256), 512, 0, stream>>>(
        A2, B2, weights, 3072, 3072, 3072, M_FACTS);

    softmax_rows_t<true><<<dim3(N_ROWS), 256, 0, stream>>>(weights, Wb);

    // gemm2: BM=128 -> grid (64,4) = 256 blocks = 1/CU, no split-K.
    gemm_big<1><<<dim3(N_ROWS / 128, D_DIM / 256), 512, 0, stream>>>(
        Wb, Ft, outputs, M_FACTS, M_FACTS, M_FACTS, D_DIM);
  } else if (t2) {
    __bf16* Ft = (__bf16*)(ws + 0 * MB);
    __bf16* Eh = (__bf16*)(ws + 16 * MB);
    __bf16* El = (__bf16*)(ws + 32 * MB);
    __bf16* Fh = (__bf16*)(ws + 48 * MB);
    __bf16* Fl = (__bf16*)(ws + 64 * MB);
    __bf16* Wb = (__bf16*)(ws + 16 * MB);

    transpose_f_bf16<<<dim3(M_FACTS / 64, D_DIM / 64), 256, 0, stream>>>(F, Ft);
    split_hi_lo<<<dim3((N_ROWS * D_DIM) / 1024), 256, 0, stream>>>(E, Eh, El);
    split_hi_lo<<<dim3((M_FACTS * D_DIM) / 1024), 256, 0, stream>>>(F, Fh, Fl);
    gemm1_fast<<<dim3(N_ROWS / BM, M_FACTS / BN), 256, 0, stream>>>(Eh, El, Fh, Fl,
                                                                    weights, 0);
    const int HALF = N_ROWS / 2;
    for (int h = 0; h < 2; h++) {
      float* Wchunk = weights + (size_t)h * HALF * M_FACTS;
      softmax_rows_t<true><<<dim3(HALF), 256, 0, stream>>>(Wchunk, Wb);
      gemm2_reg<<<dim3(HALF / BM, D_DIM / BN), 256, 0, stream>>>(Wb, Ft, outputs, h * HALF);
    }
  } else {
    __bf16* Ft = (__bf16*)ws;  // 16 MiB
    if (hasFtOnly) {
      transpose_f_bf16<<<dim3(M_FACTS / 64, D_DIM / 64), 256, 0, stream>>>(F, Ft);
    }
    gemm1_energy<<<dim3(N_ROWS / BM, M_FACTS / BN), 256, 0, stream>>>(E, F, weights);
    softmax_rows_t<false><<<dim3(N_ROWS), 256, 0, stream>>>(weights, nullptr);
    if (hasFtOnly) {
      gemm2_mid<<<dim3(N_ROWS / BM, D_DIM / BN), 256, 0, stream>>>(weights, Ft, outputs);
    } else {
      gemm2_out<<<dim3(N_ROWS / BM, D_DIM / BN), 256, 0, stream>>>(weights, F, outputs);
    }
  }
}